// Round 4
// baseline (3010.398 us; speedup 1.0000x reference)
//
#include <hip/hip_runtime.h>

#define EPS 1e-5f
#define SLOPE 0.1f
#define DIM 128
#define DE 64
#define RNUM 7
#define RD (RNUM * DIM)   // 896
#define NPB 4             // nodes per block in fused scatter
#define TP 132            // padded LDS stride for 128-wide tiles
#define YP 68             // padded LDS stride for 64-wide tiles

__device__ __forceinline__ float lrelu(float x) { return x >= 0.f ? x : SLOPE * x; }
__device__ __forceinline__ void atomAddF(float* p, float v) { unsafeAtomicAdd(p, v); }

// ---------------- column stats: out[0..F) = sum, out[F..2F) = sumsq ----------------
template<int F, int BLK>
__global__ void colstats(const float* __restrict__ x, int nrows, float* __restrict__ out) {
  constexpr int G = BLK / F;
  int f = threadIdx.x % F;
  int g = threadIdx.x / F;
  float s = 0.f, q = 0.f;
  for (int r = blockIdx.x * G + g; r < nrows; r += gridDim.x * G) {
    float v = x[(size_t)r * F + f];
    s += v; q += v * v;
  }
  if constexpr (G > 1) {
    __shared__ float ls[BLK], lq[BLK];
    ls[threadIdx.x] = s; lq[threadIdx.x] = q;
    __syncthreads();
    if (g == 0) {
      #pragma unroll
      for (int i = 1; i < G; i++) { s += ls[i * F + f]; q += lq[i * F + f]; }
    }
  }
  if (g == 0) { atomAddF(&out[f], s); atomAddF(&out[F + f], q); }
}

// ---------------- y = lrelu(bn(xin)) @ W (+bias) (+resid); optional col-stats of y ---
// 128 threads, 32-row tile. Thread t: cols 8*(t&15)..+7, rows 4*(t>>4)..+3.
// 4x8 per-thread tile: 4 ds_read_b128 per k-group vs 128 FMAs -> VALU-bound.
template<bool HAS_BIAS, bool RESID, bool STATS>
__global__ __launch_bounds__(128) void mlp128(
    const float* __restrict__ xin, const float* __restrict__ W,
    const float* __restrict__ bias,
    const float* __restrict__ bng, const float* __restrict__ bnb,
    const float* __restrict__ stats_in, float invN, int N,
    const float* __restrict__ resid,
    float* __restrict__ out, float* __restrict__ stats_out) {
  __shared__ float tile[32 * TP];
  int t = threadIdx.x;
  float a, c;
  {
    float mean = stats_in[t] * invN;
    float var = stats_in[DIM + t] * invN - mean * mean;
    a = bng[t] * rsqrtf(var + EPS);
    c = bnb[t] - mean * a;
  }
  int r0 = blockIdx.x * 32;
  int nr = min(32, N - r0);
  for (int r = 0; r < 32; r++) {
    float v = 0.f;
    if (r < nr) {
      v = xin[(size_t)(r0 + r) * DIM + t];
      v = lrelu(v * a + c);
    }
    tile[r * TP + t] = v;
  }
  __syncthreads();
  int cg = t & 15, rg = t >> 4;
  int c0 = cg * 8;
  float acc[4][8];
  #pragma unroll
  for (int rr = 0; rr < 4; rr++)
    #pragma unroll
    for (int j = 0; j < 8; j++) acc[rr][j] = 0.f;
  const float4* W4 = (const float4*)W;
  #pragma unroll 2
  for (int k = 0; k < DIM; k += 4) {
    float4 wa0 = W4[(k + 0) * 32 + cg * 2], wb0 = W4[(k + 0) * 32 + cg * 2 + 1];
    float4 wa1 = W4[(k + 1) * 32 + cg * 2], wb1 = W4[(k + 1) * 32 + cg * 2 + 1];
    float4 wa2 = W4[(k + 2) * 32 + cg * 2], wb2 = W4[(k + 2) * 32 + cg * 2 + 1];
    float4 wa3 = W4[(k + 3) * 32 + cg * 2], wb3 = W4[(k + 3) * 32 + cg * 2 + 1];
    #pragma unroll
    for (int rr = 0; rr < 4; rr++) {
      float4 tv = *(const float4*)&tile[(rg * 4 + rr) * TP + k];
      acc[rr][0] += tv.x * wa0.x + tv.y * wa1.x + tv.z * wa2.x + tv.w * wa3.x;
      acc[rr][1] += tv.x * wa0.y + tv.y * wa1.y + tv.z * wa2.y + tv.w * wa3.y;
      acc[rr][2] += tv.x * wa0.z + tv.y * wa1.z + tv.z * wa2.z + tv.w * wa3.z;
      acc[rr][3] += tv.x * wa0.w + tv.y * wa1.w + tv.z * wa2.w + tv.w * wa3.w;
      acc[rr][4] += tv.x * wb0.x + tv.y * wb1.x + tv.z * wb2.x + tv.w * wb3.x;
      acc[rr][5] += tv.x * wb0.y + tv.y * wb1.y + tv.z * wb2.y + tv.w * wb3.y;
      acc[rr][6] += tv.x * wb0.z + tv.y * wb1.z + tv.z * wb2.z + tv.w * wb3.z;
      acc[rr][7] += tv.x * wb0.w + tv.y * wb1.w + tv.z * wb2.w + tv.w * wb3.w;
    }
  }
  float bv[8];
  #pragma unroll
  for (int j = 0; j < 8; j++) bv[j] = 0.f;
  if (HAS_BIAS) {
    float4 ba = ((const float4*)bias)[cg * 2], bb = ((const float4*)bias)[cg * 2 + 1];
    bv[0]=ba.x; bv[1]=ba.y; bv[2]=ba.z; bv[3]=ba.w; bv[4]=bb.x; bv[5]=bb.y; bv[6]=bb.z; bv[7]=bb.w;
  }
  float s[8], q[8];
  #pragma unroll
  for (int j = 0; j < 8; j++) { s[j] = 0.f; q[j] = 0.f; }
  #pragma unroll
  for (int rr = 0; rr < 4; rr++) {
    int r = rg * 4 + rr;
    if (r < nr) {
      float o[8];
      #pragma unroll
      for (int j = 0; j < 8; j++) o[j] = acc[rr][j] + bv[j];
      if (RESID) {
        float4 ra = *(const float4*)&resid[(size_t)(r0 + r) * DIM + c0];
        float4 rb = *(const float4*)&resid[(size_t)(r0 + r) * DIM + c0 + 4];
        o[0]+=ra.x; o[1]+=ra.y; o[2]+=ra.z; o[3]+=ra.w;
        o[4]+=rb.x; o[5]+=rb.y; o[6]+=rb.z; o[7]+=rb.w;
      }
      *(float4*)&out[(size_t)(r0 + r) * DIM + c0]     = make_float4(o[0], o[1], o[2], o[3]);
      *(float4*)&out[(size_t)(r0 + r) * DIM + c0 + 4] = make_float4(o[4], o[5], o[6], o[7]);
      if (STATS) {
        #pragma unroll
        for (int j = 0; j < 8; j++) { s[j] += o[j]; q[j] += o[j] * o[j]; }
      }
    }
  }
  if (STATS) {
    __syncthreads();
    float* reds = tile;
    float* redq = tile + 1024;
    #pragma unroll
    for (int j = 0; j < 8; j++) { reds[rg * DIM + c0 + j] = s[j]; redq[rg * DIM + c0 + j] = q[j]; }
    __syncthreads();
    if (rg == 0) {
      #pragma unroll
      for (int j = 0; j < 8; j++) {
        int cl = c0 + j;
        float ss = 0.f, qq = 0.f;
        #pragma unroll
        for (int g = 0; g < 8; g++) { ss += reds[g * DIM + cl]; qq += redq[g * DIM + cl]; }
        atomAddF(&stats_out[cl], ss);
        atomAddF(&stats_out[DIM + cl], qq);
      }
    }
  }
}

// ---------------- out1 = lrelu(bn896(update)) @ lin_W ; col-stats of out1 ----------
__global__ __launch_bounds__(128) void lin_mlp(
    const float* __restrict__ upd, const float* __restrict__ W,
    const float* __restrict__ bng, const float* __restrict__ bnb,
    const float* __restrict__ stats_in, float invN, int N,
    float* __restrict__ out, float* __restrict__ stats_out) {
  __shared__ float tile[32 * TP];
  int t = threadIdx.x;
  int r0 = blockIdx.x * 32;
  int nr = min(32, N - r0);
  int cg = t & 15, rg = t >> 4;
  int c0 = cg * 8;
  float acc[4][8];
  #pragma unroll
  for (int rr = 0; rr < 4; rr++)
    #pragma unroll
    for (int j = 0; j < 8; j++) acc[rr][j] = 0.f;
  const float4* W4 = (const float4*)W;
  for (int kt = 0; kt < RNUM; kt++) {
    int cb = kt * DIM;
    float a, c;
    {
      int col = cb + t;
      float mean = stats_in[col] * invN;
      float var = stats_in[RD + col] * invN - mean * mean;
      a = bng[col] * rsqrtf(var + EPS);
      c = bnb[col] - mean * a;
    }
    for (int r = 0; r < 32; r++) {
      float v = 0.f;
      if (r < nr) {
        v = upd[(size_t)(r0 + r) * RD + cb + t];
        v = lrelu(v * a + c);
      }
      tile[r * TP + t] = v;
    }
    __syncthreads();
    #pragma unroll 2
    for (int k = 0; k < DIM; k += 4) {
      float4 wa0 = W4[(cb + k + 0) * 32 + cg * 2], wb0 = W4[(cb + k + 0) * 32 + cg * 2 + 1];
      float4 wa1 = W4[(cb + k + 1) * 32 + cg * 2], wb1 = W4[(cb + k + 1) * 32 + cg * 2 + 1];
      float4 wa2 = W4[(cb + k + 2) * 32 + cg * 2], wb2 = W4[(cb + k + 2) * 32 + cg * 2 + 1];
      float4 wa3 = W4[(cb + k + 3) * 32 + cg * 2], wb3 = W4[(cb + k + 3) * 32 + cg * 2 + 1];
      #pragma unroll
      for (int rr = 0; rr < 4; rr++) {
        float4 tv = *(const float4*)&tile[(rg * 4 + rr) * TP + k];
        acc[rr][0] += tv.x * wa0.x + tv.y * wa1.x + tv.z * wa2.x + tv.w * wa3.x;
        acc[rr][1] += tv.x * wa0.y + tv.y * wa1.y + tv.z * wa2.y + tv.w * wa3.y;
        acc[rr][2] += tv.x * wa0.z + tv.y * wa1.z + tv.z * wa2.z + tv.w * wa3.z;
        acc[rr][3] += tv.x * wa0.w + tv.y * wa1.w + tv.z * wa2.w + tv.w * wa3.w;
        acc[rr][4] += tv.x * wb0.x + tv.y * wb1.x + tv.z * wb2.x + tv.w * wb3.x;
        acc[rr][5] += tv.x * wb0.y + tv.y * wb1.y + tv.z * wb2.y + tv.w * wb3.y;
        acc[rr][6] += tv.x * wb0.z + tv.y * wb1.z + tv.z * wb2.z + tv.w * wb3.z;
        acc[rr][7] += tv.x * wb0.w + tv.y * wb1.w + tv.z * wb2.w + tv.w * wb3.w;
      }
    }
    __syncthreads();
  }
  float s[8], q[8];
  #pragma unroll
  for (int j = 0; j < 8; j++) { s[j] = 0.f; q[j] = 0.f; }
  #pragma unroll
  for (int rr = 0; rr < 4; rr++) {
    int r = rg * 4 + rr;
    if (r < nr) {
      *(float4*)&out[(size_t)(r0 + r) * DIM + c0]     = make_float4(acc[rr][0], acc[rr][1], acc[rr][2], acc[rr][3]);
      *(float4*)&out[(size_t)(r0 + r) * DIM + c0 + 4] = make_float4(acc[rr][4], acc[rr][5], acc[rr][6], acc[rr][7]);
      #pragma unroll
      for (int j = 0; j < 8; j++) { s[j] += acc[rr][j]; q[j] += acc[rr][j] * acc[rr][j]; }
    }
  }
  __syncthreads();
  float* reds = tile;
  float* redq = tile + 1024;
  #pragma unroll
  for (int j = 0; j < 8; j++) { reds[rg * DIM + c0 + j] = s[j]; redq[rg * DIM + c0 + j] = q[j]; }
  __syncthreads();
  if (rg == 0) {
    #pragma unroll
    for (int j = 0; j < 8; j++) {
      int cl = c0 + j;
      float ss = 0.f, qq = 0.f;
      #pragma unroll
      for (int g = 0; g < 8; g++) { ss += reds[g * DIM + cl]; qq += redq[g * DIM + cl]; }
      atomAddF(&stats_out[cl], ss);
      atomAddF(&stats_out[DIM + cl], qq);
    }
  }
}

// ---------------- Gram of Y = lrelu(bn1(h_e)): per-block partials (no atomics) -----
__global__ __launch_bounds__(256) void gram_kernel(
    const float* __restrict__ he, int E,
    const float* __restrict__ g1, const float* __restrict__ b1,
    const float* __restrict__ s_he, float invE,
    float* __restrict__ parts, int tilesPerBlock) {
  __shared__ float yt[32 * DE];
  int t = threadIdx.x;
  int f = t & 63;
  float a, c;
  {
    float mean = s_he[f] * invE;
    float var = s_he[DE + f] * invE - mean * mean;
    a = g1[f] * rsqrtf(var + EPS);
    c = b1[f] - mean * a;
  }
  int k1b = t >> 4, k2b = t & 15;
  float accG[4][4];
  #pragma unroll
  for (int i = 0; i < 4; i++) { accG[i][0]=0.f; accG[i][1]=0.f; accG[i][2]=0.f; accG[i][3]=0.f; }
  float colsum = 0.f;
  long long tile0 = (long long)blockIdx.x * tilesPerBlock;
  for (int tt = 0; tt < tilesPerBlock; tt++) {
    int e0 = (int)((tile0 + tt) * 32);
    if (e0 >= E) break;
    __syncthreads();
    #pragma unroll
    for (int i = 0; i < 8; i++) {
      int r = (t + i * 256) >> 6;
      int e = e0 + r;
      float v = 0.f;
      if (e < E) v = lrelu(he[(size_t)e * DE + f] * a + c);
      yt[r * DE + f] = v;
      colsum += v;
    }
    __syncthreads();
    #pragma unroll 4
    for (int r = 0; r < 32; r++) {
      float4 ya = *(const float4*)&yt[r * DE + k1b * 4];
      float4 yb = *(const float4*)&yt[r * DE + k2b * 4];
      accG[0][0] += ya.x * yb.x; accG[0][1] += ya.x * yb.y; accG[0][2] += ya.x * yb.z; accG[0][3] += ya.x * yb.w;
      accG[1][0] += ya.y * yb.x; accG[1][1] += ya.y * yb.y; accG[1][2] += ya.y * yb.z; accG[1][3] += ya.y * yb.w;
      accG[2][0] += ya.z * yb.x; accG[2][1] += ya.z * yb.y; accG[2][2] += ya.z * yb.z; accG[2][3] += ya.z * yb.w;
      accG[3][0] += ya.w * yb.x; accG[3][1] += ya.w * yb.y; accG[3][2] += ya.w * yb.z; accG[3][3] += ya.w * yb.w;
    }
  }
  __syncthreads();
  yt[t] = colsum;
  __syncthreads();
  float* outp = parts + (size_t)blockIdx.x * 4160;
  #pragma unroll
  for (int i = 0; i < 4; i++)
    #pragma unroll
    for (int j = 0; j < 4; j++)
      outp[(k1b * 4 + i) * DE + k2b * 4 + j] = accG[i][j];
  if (t < DE) outp[4096 + t] = yt[t] + yt[t + 64] + yt[t + 128] + yt[t + 192];
}

__global__ __launch_bounds__(256) void gram_reduce(const float* __restrict__ parts, int P,
    float* __restrict__ gram, float* __restrict__ gcol) {
  int j = blockIdx.x * 256 + threadIdx.x;
  if (j >= 4160) return;
  float s = 0.f;
  for (int p = 0; p < P; p++) s += parts[(size_t)p * 4160 + j];
  if (j < 4096) gram[j] = s; else gcol[j - 4096] = s;
}

// ---------------- edge-BN2 analytic stats: q_j = w_j^T G w_j / E, m1_j = wbar.w_j ---
__global__ __launch_bounds__(128) void ebn2_partial(
    const float* __restrict__ gram, const float* __restrict__ gcol,
    const float* __restrict__ eW, float invE,
    float* __restrict__ q, float* __restrict__ m1) {
  int j = threadIdx.x;
  int k1 = blockIdx.x;
  float wk1 = eW[k1 * DIM + j];
  float s = 0.f;
  for (int k2 = 0; k2 < DE; k2++) s += eW[k2 * DIM + j] * gram[k1 * DE + k2];
  atomAddF(&q[j], wk1 * s * invE);
  if (k1 == 0) {
    float m = 0.f;
    for (int k = 0; k < DE; k++) m += gcol[k] * eW[k * DIM + j];
    m1[j] = m * invE;
  }
}

// ---------------- CSR build -------------------------------------------------------
__global__ void count_k(const int* __restrict__ nout, int E, int* __restrict__ cnt) {
  for (int e = blockIdx.x * blockDim.x + threadIdx.x; e < E; e += gridDim.x * blockDim.x)
    atomicAdd(&cnt[nout[e]], 1);
}

__global__ __launch_bounds__(256) void scan1(const int* __restrict__ in, int n,
    int* __restrict__ excl, int* __restrict__ sums) {
  __shared__ int s[256];
  int i = blockIdx.x * 256 + threadIdx.x;
  int v = (i < n) ? in[i] : 0;
  s[threadIdx.x] = v; __syncthreads();
  for (int off = 1; off < 256; off <<= 1) {
    int x = (threadIdx.x >= off) ? s[threadIdx.x - off] : 0;
    __syncthreads(); s[threadIdx.x] += x; __syncthreads();
  }
  if (i < n) excl[i] = s[threadIdx.x] - v;
  if (threadIdx.x == 255) sums[blockIdx.x] = s[255];
}

__global__ __launch_bounds__(1024) void scan2(int* __restrict__ sums, int nch) {
  __shared__ int s[1024];
  int t = threadIdx.x;
  int v = (t < nch) ? sums[t] : 0;
  s[t] = v; __syncthreads();
  for (int off = 1; off < 1024; off <<= 1) {
    int x = (t >= off) ? s[t - off] : 0;
    __syncthreads(); s[t] += x; __syncthreads();
  }
  if (t < nch) sums[t] = s[t] - v;
}

__global__ __launch_bounds__(256) void scan3(const int* __restrict__ excl,
    const int* __restrict__ sums, int n, int E,
    int* __restrict__ base, int* __restrict__ cursor) {
  int i = blockIdx.x * 256 + threadIdx.x;
  if (i < n) { int b = excl[i] + sums[blockIdx.x]; base[i] = b; cursor[i] = b; }
  if (i == 0) base[n] = E;
}

__global__ void scatter_k(const int* __restrict__ nout, const int* __restrict__ nin,
    const int* __restrict__ rel, int E, int* __restrict__ cursor, int2* __restrict__ elist2) {
  for (int e = blockIdx.x * blockDim.x + threadIdx.x; e < E; e += gridDim.x * blockDim.x) {
    int n = nout[e];
    int pos = atomicAdd(&cursor[n], 1);
    elist2[pos] = make_int2(e, (nin[e] << 3) | rel[e]);
  }
}

// ---------------- fused: sorted-edge GEMM + bn2 + lrelu + x1 gather + LDS scatter --
__global__ __launch_bounds__(128) void fused_edge_scatter(
    const float* __restrict__ he, const int2* __restrict__ elist2,
    const int* __restrict__ base, const float* __restrict__ eW,
    const float* __restrict__ eg1, const float* __restrict__ eb1,
    const float* __restrict__ s_he, float invE,
    const float* __restrict__ qv, const float* __restrict__ m1v,
    const float* __restrict__ eg2, const float* __restrict__ eb2,
    const float* __restrict__ x1, const float* __restrict__ s_x1,
    const float* __restrict__ ig2, const float* __restrict__ ib2, float invN,
    int N, float* __restrict__ upd) {
  __shared__ float accs[NPB * RD];         // 14336 B per-node accumulators
  __shared__ float yt[32 * YP];            // 8704 B padded edge-Y tile
  __shared__ float a2s[DIM], c2s[DIM], axs[DIM], cxs[DIM];
  __shared__ int s_eid[32], s_nl[32], s_gr[32];
  int t = threadIdx.x;
  {
    float m = m1v[t];
    float aa = eg2[t] * rsqrtf(qv[t] - m * m + EPS);
    a2s[t] = aa;
    c2s[t] = eb2[t] - m * aa;              // e_b bias cancels through BN
    float mx = s_x1[t] * invN;
    float vx = s_x1[DIM + t] * invN - mx * mx;
    float ax = ig2[t] * rsqrtf(vx + EPS);
    axs[t] = ax;
    cxs[t] = ib2[t] - mx * ax;
  }
  int f = t & 63;
  float ae1, ce1;
  {
    float me = s_he[f] * invE;
    float ve = s_he[DE + f] * invE - me * me;
    ae1 = eg1[f] * rsqrtf(ve + EPS);
    ce1 = eb1[f] - me * ae1;
  }
  for (int i = t; i < NPB * RD; i += 128) accs[i] = 0.f;
  int n0 = blockIdx.x * NPB;
  int estart = base[n0];
  int eend = base[min(n0 + NPB, N)];
  int bb1 = base[min(n0 + 1, N)];
  int bb2 = base[min(n0 + 2, N)];
  int bb3 = base[min(n0 + 3, N)];
  int cg = t & 15, rg = t >> 4;
  int c0 = cg * 8;
  const float4* W4 = (const float4*)eW;
  for (int e0 = estart; e0 < eend; e0 += 32) {
    __syncthreads();   // (1) prev iter's GEMM/epilogue done reading yt, s_gr, s_nl
    if (t < 32) {
      int pos = e0 + t;
      int2 ee = (pos < eend) ? elist2[pos] : make_int2(0, 0);
      s_eid[t] = ee.x;
      s_gr[t] = ee.y;
      s_nl[t] = (pos >= bb3) ? 3 : (pos >= bb2) ? 2 : (pos >= bb1) ? 1 : 0;
    }
    __syncthreads();   // (2) s_eid visible to all waves before staging reads it
    #pragma unroll
    for (int i = 0; i < 16; i++) {
      int r = (t + i * 128) >> 6;
      float v = 0.f;
      if (e0 + r < eend) v = lrelu(he[(size_t)s_eid[r] * DE + f] * ae1 + ce1);
      yt[r * YP + f] = v;
    }
    __syncthreads();   // (3) yt visible before GEMM reads
    float acc[4][8];
    #pragma unroll
    for (int rr = 0; rr < 4; rr++)
      #pragma unroll
      for (int j = 0; j < 8; j++) acc[rr][j] = 0.f;
    #pragma unroll 2
    for (int k = 0; k < DE; k += 4) {
      float4 wa0 = W4[(k + 0) * 32 + cg * 2], wb0 = W4[(k + 0) * 32 + cg * 2 + 1];
      float4 wa1 = W4[(k + 1) * 32 + cg * 2], wb1 = W4[(k + 1) * 32 + cg * 2 + 1];
      float4 wa2 = W4[(k + 2) * 32 + cg * 2], wb2 = W4[(k + 2) * 32 + cg * 2 + 1];
      float4 wa3 = W4[(k + 3) * 32 + cg * 2], wb3 = W4[(k + 3) * 32 + cg * 2 + 1];
      #pragma unroll
      for (int rr = 0; rr < 4; rr++) {
        float4 tv = *(const float4*)&yt[(rg * 4 + rr) * YP + k];
        acc[rr][0] += tv.x * wa0.x + tv.y * wa1.x + tv.z * wa2.x + tv.w * wa3.x;
        acc[rr][1] += tv.x * wa0.y + tv.y * wa1.y + tv.z * wa2.y + tv.w * wa3.y;
        acc[rr][2] += tv.x * wa0.z + tv.y * wa1.z + tv.z * wa2.z + tv.w * wa3.z;
        acc[rr][3] += tv.x * wa0.w + tv.y * wa1.w + tv.z * wa2.w + tv.w * wa3.w;
        acc[rr][4] += tv.x * wb0.x + tv.y * wb1.x + tv.z * wb2.x + tv.w * wb3.x;
        acc[rr][5] += tv.x * wb0.y + tv.y * wb1.y + tv.z * wb2.y + tv.w * wb3.y;
        acc[rr][6] += tv.x * wb0.z + tv.y * wb1.z + tv.z * wb2.z + tv.w * wb3.z;
        acc[rr][7] += tv.x * wb0.w + tv.y * wb1.w + tv.z * wb2.w + tv.w * wb3.w;
      }
    }
    {
      float4 a2a = *(const float4*)&a2s[c0], a2b = *(const float4*)&a2s[c0 + 4];
      float4 c2a = *(const float4*)&c2s[c0], c2b = *(const float4*)&c2s[c0 + 4];
      float4 axa = *(const float4*)&axs[c0], axb = *(const float4*)&axs[c0 + 4];
      float4 cxa = *(const float4*)&cxs[c0], cxb = *(const float4*)&cxs[c0 + 4];
      #pragma unroll
      for (int rr = 0; rr < 4; rr++) {
        int r = rg * 4 + rr;
        if (e0 + r < eend) {
          int y = s_gr[r];
          const float* xr = &x1[(size_t)(y >> 3) * DIM + c0];
          float4 xva = *(const float4*)xr;
          float4 xvb = *(const float4*)(xr + 4);
          float* ap = &accs[s_nl[r] * RD + (y & 7) * DIM + c0];
          atomicAdd(ap + 0, lrelu(acc[rr][0] * a2a.x + c2a.x) + lrelu(xva.x * axa.x + cxa.x));
          atomicAdd(ap + 1, lrelu(acc[rr][1] * a2a.y + c2a.y) + lrelu(xva.y * axa.y + cxa.y));
          atomicAdd(ap + 2, lrelu(acc[rr][2] * a2a.z + c2a.z) + lrelu(xva.z * axa.z + cxa.z));
          atomicAdd(ap + 3, lrelu(acc[rr][3] * a2a.w + c2a.w) + lrelu(xva.w * axa.w + cxa.w));
          atomicAdd(ap + 4, lrelu(acc[rr][4] * a2b.x + c2b.x) + lrelu(xvb.x * axb.x + cxb.x));
          atomicAdd(ap + 5, lrelu(acc[rr][5] * a2b.y + c2b.y) + lrelu(xvb.y * axb.y + cxb.y));
          atomicAdd(ap + 6, lrelu(acc[rr][6] * a2b.z + c2b.z) + lrelu(xvb.z * axb.z + cxb.z));
          atomicAdd(ap + 7, lrelu(acc[rr][7] * a2b.w + c2b.w) + lrelu(xvb.w * axb.w + cxb.w));
        }
      }
    }
  }
  __syncthreads();
  int nn = min(NPB, N - n0);
  for (int i = t; i < nn * RD; i += 128)
    upd[(size_t)n0 * RD + i] = accs[i];
}

extern "C" void kernel_launch(void* const* d_in, const int* in_sizes, int n_in,
                              void* d_out, int out_size, void* d_ws, size_t ws_size,
                              hipStream_t stream) {
  const float* h_v      = (const float*)d_in[0];
  const int*   node_in  = (const int*)d_in[1];
  const int*   node_out = (const int*)d_in[2];
  const int*   rel      = (const int*)d_in[3];
  const float* h_e      = (const float*)d_in[4];
  const float* in_bn1_g = (const float*)d_in[5];
  const float* in_bn1_b = (const float*)d_in[6];
  const float* in_W     = (const float*)d_in[7];
  const float* in_b     = (const float*)d_in[8];
  const float* in_bn2_g = (const float*)d_in[9];
  const float* in_bn2_b = (const float*)d_in[10];
  const float* e_bn1_g  = (const float*)d_in[11];
  const float* e_bn1_b  = (const float*)d_in[12];
  const float* e_W      = (const float*)d_in[13];
  // const float* e_b   = (const float*)d_in[14];  // cancels through edge bn2
  const float* e_bn2_g  = (const float*)d_in[15];
  const float* e_bn2_b  = (const float*)d_in[16];
  const float* lin_bn_g = (const float*)d_in[17];
  const float* lin_bn_b = (const float*)d_in[18];
  const float* lin_W    = (const float*)d_in[19];
  const float* out_bn_g = (const float*)d_in[20];
  const float* out_bn_b = (const float*)d_in[21];
  const float* out_W    = (const float*)d_in[22];

  int N = in_sizes[0] / DIM;
  int E = in_sizes[1];
  if (N <= 0 || E <= 0) return;
  float invN = 1.f / (float)N;
  float invE = 1.f / (float)E;

  // ---- workspace layout ----
  float* ws   = (float*)d_ws;
  float* upd  = ws;                                   // N * 896 floats
  float* x1   = upd + (size_t)N * RD;                 // N * 128 (raw x1; reused as out1)
  float* stats = x1 + (size_t)N * DIM;
  float* s_hv = stats;            // 256
  float* s_x1 = s_hv + 2 * DIM;   // 256
  float* s_he = s_x1 + 2 * DIM;   // 128
  float* qv   = s_he + 2 * DE;    // 128
  float* m1v  = qv + DIM;         // 128
  float* s_up = m1v + DIM;        // 1792
  float* s_o1 = s_up + 2 * RD;    // 256
  float* gram = s_o1 + 2 * DIM;   // 4096 (written fully by gram_reduce)
  float* gcol = gram + DE * DE;   // 64
  float* statsEnd = gcol + DE;
  size_t statsFloats = (size_t)(statsEnd - stats);    // 7104
  int2* elist2 = (int2*)statsEnd;                     // E int2
  int* cnt    = (int*)(elist2 + E);                   // N   (aliased as excl)
  int* sums   = cnt + N;                              // 1024
  int* base   = sums + 1024;                          // N+1
  int* cursor = base + N + 1;                         // N
  float* parts = upd;                                 // gram partials alias upd (consumed before upd written)

  int nBlk32 = (N + 31) / 32;
  int nch = (N + 255) / 256;

  hipMemsetAsync(stats, 0, statsFloats * sizeof(float), stream);
  hipMemsetAsync(cnt, 0, (size_t)N * sizeof(int), stream);

  // node path
  colstats<DIM, 256><<<512, 256, 0, stream>>>(h_v, N, s_hv);
  mlp128<true, false, true><<<nBlk32, 128, 0, stream>>>(
      h_v, in_W, in_b, in_bn1_g, in_bn1_b, s_hv, invN, N, nullptr, x1, s_x1);

  // edge stats path
  colstats<DE, 256><<<1024, 256, 0, stream>>>(h_e, E, s_he);

  // CSR build
  count_k<<<1024, 256, 0, stream>>>(node_out, E, cnt);
  scan1<<<nch, 256, 0, stream>>>(cnt, N, cnt, sums);
  scan2<<<1, 1024, 0, stream>>>(sums, nch);
  scan3<<<nch, 256, 0, stream>>>(cnt, sums, N, E, base, cursor);
  scatter_k<<<1024, 256, 0, stream>>>(node_out, node_in, rel, E, cursor, elist2);

  // Gram -> analytic edge-bn2 stats (partials aliased on upd, consumed before fused)
  {
    int tiles = 32;
    int P = (E + 32 * tiles - 1) / (32 * tiles);
    gram_kernel<<<P, 256, 0, stream>>>(h_e, E, e_bn1_g, e_bn1_b, s_he, invE, parts, tiles);
    gram_reduce<<<(4160 + 255) / 256, 256, 0, stream>>>(parts, P, gram, gcol);
  }
  ebn2_partial<<<DE, 128, 0, stream>>>(gram, gcol, e_W, invE, qv, m1v);

  // fused sorted-edge GEMM + scatter (no global atomics, writes every upd row)
  fused_edge_scatter<<<(N + NPB - 1) / NPB, 128, 0, stream>>>(
      h_e, elist2, base, e_W, e_bn1_g, e_bn1_b, s_he, invE,
      qv, m1v, e_bn2_g, e_bn2_b, x1, s_x1, in_bn2_g, in_bn2_b, invN,
      N, upd);

  // tail: bn896 -> lin -> bn -> out (+residual)
  colstats<RD, RD><<<448, RD, 0, stream>>>(upd, N, s_up);
  lin_mlp<<<nBlk32, 128, 0, stream>>>(upd, lin_W, lin_bn_g, lin_bn_b, s_up, invN, N,
                                      x1, s_o1);   // x1 reused as out1
  mlp128<false, true, false><<<nBlk32, 128, 0, stream>>>(
      x1, out_W, nullptr, out_bn_g, out_bn_b, s_o1, invN, N, h_v, (float*)d_out, nullptr);
}